// Round 6
// baseline (383.893 us; speedup 1.0000x reference)
//
#include <hip/hip_runtime.h>
#include <hip/hip_bf16.h>
#include <math.h>

#define N_SKILLS 16
#define RLORA 16
#define IN_F 1024
#define OUT_F 1024
#define KD 1024
#define ND 1024

typedef __attribute__((ext_vector_type(8))) short s16x8;
typedef __attribute__((ext_vector_type(4))) float f32x4;

__device__ __forceinline__ unsigned short f2bf(float f) {
  unsigned int u = __float_as_uint(f);
  u += 0x7fffu + ((u >> 16) & 1u);
  return (unsigned short)(u >> 16);
}

#define GLDS(gsrc, ldst)                                                       \
  __builtin_amdgcn_global_load_lds(                                            \
      (const __attribute__((address_space(1))) unsigned int*)(gsrc),           \
      (__attribute__((address_space(3))) unsigned int*)(ldst), 16, 0, 0)

// ---------------------------------------------------------------------------
// Kernel 1: routing -> per-sample LoRA weights wA (B,IN_F,R), wB (B,R,OUT_F)
// ---------------------------------------------------------------------------
__global__ void route_wab_kernel(const float* __restrict__ skill_logits,
                                 const int* __restrict__ task_ids,
                                 const float* __restrict__ Askills,
                                 const float* __restrict__ Bskills,
                                 float* __restrict__ wA, float* __restrict__ wB) {
  __shared__ float l[N_SKILLS];
  const int bx = blockIdx.x;
  const int b = bx & 15;
  const int doB = bx >> 4;
  const int tid = threadIdx.x;
  if (tid == 0) {
    int t = task_ids[b];
    float tmp[N_SKILLS];
    float s = 0.f;
    for (int k = 0; k < N_SKILLS; ++k) {
      float v = 1.f / (1.f + expf(-skill_logits[t * N_SKILLS + k]));
      tmp[k] = v;
      s += v;
    }
    float inv = 1.f / (s + 1e-12f);
    for (int k = 0; k < N_SKILLS; ++k) l[k] = tmp[k] * inv;
  }
  __syncthreads();
  const float* src = doB ? Bskills : Askills;
  float* dst = (doB ? wB : wA) + b * 16384;
  for (int j = tid; j < 16384; j += 256) {
    float acc = 0.f;
#pragma unroll
    for (int k = 0; k < N_SKILLS; ++k) acc += l[k] * src[k * 16384 + j];
    dst[j] = acc;
  }
}

// ---------------------------------------------------------------------------
// Tile image layout (per 256x64 bf16 tile = 16384 shorts):
//   element (row, k):  region = (row>>6)*2 + (k>>5)          (8 regions)
//   off = region*2048 + ((k>>3)&3)*512 + (row&63)*8 + (k&7)
// One GLD "call" g covers regions [2g, 2g+2) = rows [g*64,+64), all k.
// ---------------------------------------------------------------------------

// Kernel 2a: A fp32 -> bf16 tiled images. Block = one 64-row quarter of a
// (mt,kt) tile. Direct global writes (non-overlapping, 256B runs per wave).
__global__ __launch_bounds__(256) void aconv_kernel(
    const float* __restrict__ A, unsigned short* __restrict__ At) {
  const int bx = blockIdx.x;  // (mt*16+kt)*4 + rp
  const int rp = bx & 3;
  const int tk = bx >> 2;
  const int mt = tk >> 4, kt = tk & 15;
  const int tid = threadIdx.x;
  const int rowl = tid >> 2, kquad = tid & 3;
  const int ks = kquad >> 1;
  const float* src =
      A + (size_t)(mt * 256 + rp * 64 + rowl) * KD + kt * 64 + kquad * 16;
  f32x4 v0 = *(const f32x4*)(src);
  f32x4 v1 = *(const f32x4*)(src + 4);
  f32x4 v2 = *(const f32x4*)(src + 8);
  f32x4 v3 = *(const f32x4*)(src + 12);
  s16x8 lo, hi;
#pragma unroll
  for (int j = 0; j < 4; ++j) {
    lo[j] = (short)f2bf(v0[j]);
    lo[j + 4] = (short)f2bf(v1[j]);
    hi[j] = (short)f2bf(v2[j]);
    hi[j + 4] = (short)f2bf(v3[j]);
  }
  unsigned short* dst = At + (size_t)tk * 16384 + (rp * 2 + ks) * 2048 +
                        (kquad & 1) * 1024 + rowl * 8;
  *(s16x8*)&dst[0] = lo;
  *(s16x8*)&dst[512] = hi;
}

// Kernel 2b: W_eff = weight + (1/R)*(wA@wB)^T, bf16 tiled images.
// Block = 64-col quarter of a (b,nt,kt) tile. grid = 16*4*16*4 = 4096.
__global__ __launch_bounds__(256) void weff_kernel(
    const float* __restrict__ weight, const float* __restrict__ wA,
    const float* __restrict__ wB, unsigned short* __restrict__ Wt) {
  __shared__ float wBs[16][64];
  __shared__ float wAs[64][16];
  const int bx = blockIdx.x;  // ((b*4+nt)*16+kt)*4 + rp
  const int rp = bx & 3;
  const int t = bx >> 2;  // b*64 + nt*16 + kt
  const int b = t >> 6;
  const int nt = (t >> 4) & 3;
  const int kt = t & 15;
  const int tid = threadIdx.x;
  for (int j = tid; j < 1024; j += 256) {
    wBs[j >> 6][j & 63] =
        wB[b * 16384 + (j >> 6) * OUT_F + nt * 256 + rp * 64 + (j & 63)];
    wAs[j >> 4][j & 15] = wA[b * 16384 + kt * 1024 + j];
  }
  __syncthreads();
  const int ol = tid >> 2, kquad = tid & 3;
  const int ks = kquad >> 1;
  const int o_loc = rp * 64 + ol;  // tile-local out-col
  const float* src =
      weight + (size_t)(nt * 256 + o_loc) * IN_F + kt * 64 + kquad * 16;
  f32x4 v0 = *(const f32x4*)(src);
  f32x4 v1 = *(const f32x4*)(src + 4);
  f32x4 v2 = *(const f32x4*)(src + 8);
  f32x4 v3 = *(const f32x4*)(src + 12);
  float wv[16];
#pragma unroll
  for (int j = 0; j < 4; ++j) {
    wv[j] = v0[j];
    wv[j + 4] = v1[j];
    wv[j + 8] = v2[j];
    wv[j + 12] = v3[j];
  }
  float wbo[16];
#pragma unroll
  for (int r = 0; r < 16; ++r) wbo[r] = wBs[r][ol];
  unsigned short res[16];
#pragma unroll
  for (int j = 0; j < 16; ++j) {
    const int il = kquad * 16 + j;
    float acc = 0.f;
#pragma unroll
    for (int r = 0; r < 16; ++r) acc += wAs[il][r] * wbo[r];
    res[j] = f2bf(wv[j] + acc * 0.0625f);
  }
  s16x8 lo, hi;
#pragma unroll
  for (int j = 0; j < 8; ++j) {
    lo[j] = (short)res[j];
    hi[j] = (short)res[j + 8];
  }
  unsigned short* dst = Wt + (size_t)t * 16384 + (rp * 2 + ks) * 2048 +
                        (kquad & 1) * 1024 + ol * 8;
  *(s16x8*)&dst[0] = lo;
  *(s16x8*)&dst[512] = hi;
}

// ---------------------------------------------------------------------------
// Kernel 3: 256x256 8-phase GEMM, BK=64, 8 waves (2Mx4N).
// COUNTED lgkm waits: phase P's MFMA consumes reads issued in phase P-1;
// wait lgkmcnt(#reads issued this phase) so this phase's reads are serviced
// UNDER the MFMA cluster (LDS pipe || matrix pipe).
// Issue plan (body t): P0: A(t+1)c0,c2->ASN; P1: A(t+1)c1,c3->ASN;
//   P2: B(t+2)c0,c1->BSC; P3: B(t+2)c2,c3->BSC.
// Clobber separation (last-read -> clobber-issue): ASN c0,c2: 4 phases;
//   ASN c1,c3: 3; BSC: 2 (reads force-serviced <=1 phase after issue).
// vmcnt gates (FIFO-traced): end-P0 vmcnt(6) drains A(t)c1,c3 [4-ph cover];
//   end-P2 vmcnt(4) drains B(t+1)x4 + A(t+1)c0,c2 [3-5 ph cover].
// Steady-state in-flight: 4..10.
// ---------------------------------------------------------------------------
#define BAR() __builtin_amdgcn_s_barrier()
#define LGKM(N)                                                 \
  {                                                             \
    asm volatile("s_waitcnt lgkmcnt(" #N ")" ::: "memory");     \
    __builtin_amdgcn_sched_barrier(0);                          \
  }
#define VMCNT(N) asm volatile("s_waitcnt vmcnt(" #N ")" ::: "memory")
#define PRIO1() __builtin_amdgcn_s_setprio(1)
#define PRIO0() __builtin_amdgcn_s_setprio(0)

#define GLD_CALL(LDSBUF, GBASE, CALLIDX)                                       \
  GLDS((GBASE) + (CALLIDX) * 4096 + wid * 512 + lane * 8,                      \
       &(LDSBUF)[(CALLIDX) * 4096 + wid * 512])

#define READ_A(BANK, LDSBUF, MH, KS)                                           \
  {                                                                            \
    _Pragma("unroll") for (int mf_ = 0; mf_ < 4; ++mf_)                        \
        BANK[mf_] = *(const s16x8*)&(                                          \
            LDSBUF)[((wr2 + (MH)) * 2 + (KS)) * 2048 + kq512 +                 \
                    (mf_ * 16 + l15) * 8];                                     \
  }

#define READ_B(LDSBUF, KS)                                                     \
  {                                                                            \
    _Pragma("unroll") for (int nf_ = 0; nf_ < 4; ++nf_)                        \
        bfr[(KS)*4 + nf_] = *(const s16x8*)&(                                  \
            LDSBUF)[(wc2 + (KS)) * 2048 + kq512 + (nf_ * 16 + l15) * 8];       \
  }

#define MFMA16(MH, ABANK, BOFF)                                                \
  {                                                                            \
    _Pragma("unroll") for (int mf_ = 0; mf_ < 4; ++mf_)                        \
        _Pragma("unroll") for (int nf_ = 0; nf_ < 4; ++nf_)                    \
            acc[(MH)*4 + mf_][nf_] = __builtin_amdgcn_mfma_f32_16x16x32_bf16(  \
                ABANK[mf_], bfr[(BOFF) + nf_], acc[(MH)*4 + mf_][nf_], 0, 0,   \
                0);                                                            \
  }

#define TILE_BODY(ASC, BSC, ASN, BSN, T)                                       \
  {                                                                            \
    const int tn_ = ((T) + 1 < 16) ? (T) + 1 : 15;                             \
    const int tnn_ = ((T) + 2 < 16) ? (T) + 2 : 15;                            \
    const unsigned short* Anx = Abase + (size_t)tn_ * 16384;                   \
    const unsigned short* Bnn = Bbase + (size_t)tnn_ * 16384;                  \
    /* P0: MFMA(a0,b0..3) [read prev-P3]; reads a1/b4..7 overlap it */         \
    READ_A(a1, ASC, 0, 1);                                                     \
    READ_B(BSC, 1);                                                            \
    GLD_CALL(ASN, Anx, 0);                                                     \
    GLD_CALL(ASN, Anx, 2);                                                     \
    BAR();                                                                     \
    LGKM(8);                                                                   \
    PRIO1(); MFMA16(0, a0, 0); PRIO0();                                        \
    VMCNT(6);                                                                  \
    BAR();                                                                     \
    /* P1 */                                                                   \
    READ_A(a0, ASC, 1, 0);                                                     \
    GLD_CALL(ASN, Anx, 1);                                                     \
    GLD_CALL(ASN, Anx, 3);                                                     \
    BAR();                                                                     \
    LGKM(4);                                                                   \
    PRIO1(); MFMA16(0, a1, 4); PRIO0();                                        \
    BAR();                                                                     \
    /* P2 */                                                                   \
    READ_A(a1, ASC, 1, 1);                                                     \
    GLD_CALL(BSC, Bnn, 0);                                                     \
    GLD_CALL(BSC, Bnn, 1);                                                     \
    BAR();                                                                     \
    LGKM(4);                                                                   \
    PRIO1(); MFMA16(1, a0, 0); PRIO0();                                        \
    VMCNT(4);                                                                  \
    BAR();                                                                     \
    /* P3 */                                                                   \
    READ_A(a0, ASN, 0, 0);                                                     \
    READ_B(BSN, 0);                                                            \
    GLD_CALL(BSC, Bnn, 2);                                                     \
    GLD_CALL(BSC, Bnn, 3);                                                     \
    BAR();                                                                     \
    LGKM(8);                                                                   \
    PRIO1(); MFMA16(1, a1, 4); PRIO0();                                        \
    BAR();                                                                     \
  }

__global__ __launch_bounds__(512) void gemm8_kernel(
    const unsigned short* __restrict__ At, const unsigned short* __restrict__ Wt,
    const float* __restrict__ bias, float* __restrict__ C) {
  __shared__ __align__(16) unsigned short Asm[2][16384];
  __shared__ __align__(16) unsigned short Bsm[2][16384];
  unsigned short* const As0 = Asm[0];
  unsigned short* const As1 = Asm[1];
  unsigned short* const Bs0 = Bsm[0];
  unsigned short* const Bs1 = Bsm[1];

  const int orig = blockIdx.x;
  const int bid = (orig & 7) * 128 + (orig >> 3);  // XCD swizzle, 1024%8==0
  const int mt = bid >> 2;                         // 0..255
  const int nt = bid & 3;                          // 0..3
  const int batch = mt >> 4;
  const unsigned short* Abase = At + (size_t)mt * 16 * 16384;
  const unsigned short* Bbase = Wt + ((size_t)batch * 4 + nt) * 16 * 16384;

  const int tid = threadIdx.x;
  const int lane = tid & 63;
  const int wid = tid >> 6;
  const int wr = wid >> 2;  // 0..1
  const int wc = wid & 3;   // 0..3
  const int wr2 = wr * 2;
  const int wc2 = wc * 2;
  const int l15 = lane & 15;
  const int kq = lane >> 4;
  const int kq512 = kq * 512;

  f32x4 acc[8][4] = {};
  s16x8 a0[4], a1[4], bfr[8];

  // Prologue: issue A(0)x4, B(0)x4, B(1)x4 (12 calls); vmcnt(4) drains
  // A(0)+B(0); leaves B(1)x4 in flight = steady-state FIFO entering body 0.
  GLD_CALL(As0, Abase, 0);
  GLD_CALL(As0, Abase, 1);
  GLD_CALL(As0, Abase, 2);
  GLD_CALL(As0, Abase, 3);
  GLD_CALL(Bs0, Bbase, 0);
  GLD_CALL(Bs0, Bbase, 1);
  GLD_CALL(Bs0, Bbase, 2);
  GLD_CALL(Bs0, Bbase, 3);
  {
    const unsigned short* B1 = Bbase + 16384;
    GLD_CALL(Bs1, B1, 0);
    GLD_CALL(Bs1, B1, 1);
    GLD_CALL(Bs1, B1, 2);
    GLD_CALL(Bs1, B1, 3);
  }
  VMCNT(4);
  BAR();
  READ_A(a0, As0, 0, 0);
  READ_B(Bs0, 0);

#pragma unroll 1
  for (int it = 0; it < 8; ++it) {
    const int t0 = it * 2;
    TILE_BODY(As0, Bs0, As1, Bs1, t0);
    TILE_BODY(As1, Bs1, As0, Bs0, t0 + 1);
  }

  // Epilogue: bias add + store fp32
  const int m0 = mt * 256, n0 = nt * 256;
#pragma unroll
  for (int n = 0; n < 4; ++n) {
    const int col = n0 + wc * 64 + n * 16 + l15;
    const float bv = bias[col];
#pragma unroll
    for (int m = 0; m < 8; ++m) {
      const int row = m0 + wr * 128 + m * 16 + kq * 4;
#pragma unroll
      for (int j = 0; j < 4; ++j)
        C[(size_t)(row + j) * ND + col] = acc[m][n][j] + bv;
    }
  }
}

// ---------------------------------------------------------------------------
extern "C" void kernel_launch(void* const* d_in, const int* in_sizes, int n_in,
                              void* d_out, int out_size, void* d_ws,
                              size_t ws_size, hipStream_t stream) {
  const float* input = (const float*)d_in[0];
  const float* skill_logits = (const float*)d_in[1];
  const float* weight = (const float*)d_in[2];
  const float* bias = (const float*)d_in[3];
  const float* Askills = (const float*)d_in[4];
  const float* Bskills = (const float*)d_in[5];
  const int* task_ids = (const int*)d_in[6];

  float* wA = (float*)d_ws;                                   // 1 MB
  float* wB = wA + 16 * 16384;                                // 1 MB
  unsigned short* Wt = (unsigned short*)(wB + 16 * 16384);    // 32 MB
  unsigned short* At = Wt + 16ull * 1024 * 1024;              // 128 MB

  route_wab_kernel<<<32, 256, 0, stream>>>(skill_logits, task_ids, Askills,
                                           Bskills, wA, wB);
  aconv_kernel<<<16384, 256, 0, stream>>>(input, At);
  weff_kernel<<<4096, 256, 0, stream>>>(weight, wA, wB, Wt);
  gemm8_kernel<<<1024, 512, 0, stream>>>(At, Wt, bias, (float*)d_out);
}

// Round 7
// 381.037 us; speedup vs baseline: 1.0075x; 1.0075x over previous
//
#include <hip/hip_runtime.h>
#include <hip/hip_bf16.h>
#include <math.h>

#define N_SKILLS 16
#define RLORA 16
#define IN_F 1024
#define OUT_F 1024
#define KD 1024
#define ND 1024
#define TILE_SH 8192  // shorts per 128x64 bf16 tile image

typedef __attribute__((ext_vector_type(8))) short s16x8;
typedef __attribute__((ext_vector_type(4))) float f32x4;
typedef __attribute__((ext_vector_type(16))) float f32x16;

__device__ __forceinline__ unsigned short f2bf(float f) {
  unsigned int u = __float_as_uint(f);
  u += 0x7fffu + ((u >> 16) & 1u);
  return (unsigned short)(u >> 16);
}

#define GLDS(gsrc, ldst)                                                       \
  __builtin_amdgcn_global_load_lds(                                            \
      (const __attribute__((address_space(1))) unsigned int*)(gsrc),           \
      (__attribute__((address_space(3))) unsigned int*)(ldst), 16, 0, 0)

// ---------------------------------------------------------------------------
// Kernel 1: routing -> per-sample LoRA weights wA (B,IN_F,R), wB (B,R,OUT_F)
// ---------------------------------------------------------------------------
__global__ void route_wab_kernel(const float* __restrict__ skill_logits,
                                 const int* __restrict__ task_ids,
                                 const float* __restrict__ Askills,
                                 const float* __restrict__ Bskills,
                                 float* __restrict__ wA, float* __restrict__ wB) {
  __shared__ float l[N_SKILLS];
  const int bx = blockIdx.x;
  const int b = bx & 15;
  const int doB = bx >> 4;
  const int tid = threadIdx.x;
  if (tid == 0) {
    int t = task_ids[b];
    float tmp[N_SKILLS];
    float s = 0.f;
    for (int k = 0; k < N_SKILLS; ++k) {
      float v = 1.f / (1.f + expf(-skill_logits[t * N_SKILLS + k]));
      tmp[k] = v;
      s += v;
    }
    float inv = 1.f / (s + 1e-12f);
    for (int k = 0; k < N_SKILLS; ++k) l[k] = tmp[k] * inv;
  }
  __syncthreads();
  const float* src = doB ? Bskills : Askills;
  float* dst = (doB ? wB : wA) + b * 16384;
  for (int j = tid; j < 16384; j += 256) {
    float acc = 0.f;
#pragma unroll
    for (int k = 0; k < N_SKILLS; ++k) acc += l[k] * src[k * 16384 + j];
    dst[j] = acc;
  }
}

// ---------------------------------------------------------------------------
// Tile image layout (per 128-row x 64-k bf16 tile = 8192 shorts):
//   short offset of (row, k) = (k>>4)*2048 + row*16 + ((k>>3)&1)*8 + (k&7)
// Linear in GLD call order: call c (0..15) = shorts [c*512, (c+1)*512).
// 32x32x16 fragment read (m0,k0): lane l -> row m0+(l&31), k k0+(l>>5)*8
//   = (k0>>4)*2048 + (m0+(l&31))*16 + (l>>5)*8   (contiguous 2KB / frag).
// ---------------------------------------------------------------------------

// Kernel 2a: A fp32 -> bf16 tile images. Block = 64-row half of (mt,kt) tile.
__global__ __launch_bounds__(256) void aconv_kernel(
    const float* __restrict__ A, unsigned short* __restrict__ At) {
  const int bx = blockIdx.x;  // (mt*16+kt)*2 + rh
  const int rh = bx & 1;
  const int tk = bx >> 1;     // mt*16 + kt
  const int mt = tk >> 4, kt = tk & 15;
  const int tid = threadIdx.x;
  const int row64 = tid >> 2, kq = tid & 3;
  const int rloc = rh * 64 + row64;
  const float* src = A + (size_t)(mt * 128 + rloc) * KD + kt * 64 + kq * 16;
  f32x4 v0 = *(const f32x4*)(src);
  f32x4 v1 = *(const f32x4*)(src + 4);
  f32x4 v2 = *(const f32x4*)(src + 8);
  f32x4 v3 = *(const f32x4*)(src + 12);
  s16x8 lo, hi;
#pragma unroll
  for (int j = 0; j < 4; ++j) {
    lo[j] = (short)f2bf(v0[j]);
    lo[j + 4] = (short)f2bf(v1[j]);
    hi[j] = (short)f2bf(v2[j]);
    hi[j + 4] = (short)f2bf(v3[j]);
  }
  unsigned short* dst = At + (size_t)tk * TILE_SH + kq * 2048 + rloc * 16;
  *(s16x8*)&dst[0] = lo;
  *(s16x8*)&dst[8] = hi;
}

// Kernel 2b: W_eff = weight + (1/R)*(wA@wB)^T, bf16 tile images.
// Block = 64-col half of (b,nt,kt) tile. grid = 16*8*16*2 = 4096.
__global__ __launch_bounds__(256) void weff_kernel(
    const float* __restrict__ weight, const float* __restrict__ wA,
    const float* __restrict__ wB, unsigned short* __restrict__ Wt) {
  __shared__ float wBs[16][64];
  __shared__ float wAs[64][16];
  const int bx = blockIdx.x;  // ((b*8+nt)*16+kt)*2 + ch
  const int ch = bx & 1;
  const int t = bx >> 1;      // (b*8+nt)*16 + kt
  const int kt = t & 15;
  const int nt = (t >> 4) & 7;
  const int b = t >> 7;
  const int tid = threadIdx.x;
  for (int j = tid; j < 1024; j += 256) {
    wBs[j >> 6][j & 63] =
        wB[b * 16384 + (j >> 6) * OUT_F + nt * 128 + ch * 64 + (j & 63)];
    wAs[j >> 4][j & 15] = wA[b * 16384 + kt * 1024 + j];
  }
  __syncthreads();
  const int ol = tid >> 2, kq = tid & 3;
  const int col_local = ch * 64 + ol;
  const int og = nt * 128 + col_local;
  const float* src = weight + (size_t)og * IN_F + kt * 64 + kq * 16;
  f32x4 v0 = *(const f32x4*)(src);
  f32x4 v1 = *(const f32x4*)(src + 4);
  f32x4 v2 = *(const f32x4*)(src + 8);
  f32x4 v3 = *(const f32x4*)(src + 12);
  float wv[16];
#pragma unroll
  for (int j = 0; j < 4; ++j) {
    wv[j] = v0[j];
    wv[j + 4] = v1[j];
    wv[j + 8] = v2[j];
    wv[j + 12] = v3[j];
  }
  float wbo[16];
#pragma unroll
  for (int r = 0; r < 16; ++r) wbo[r] = wBs[r][ol];
  unsigned short res[16];
#pragma unroll
  for (int j = 0; j < 16; ++j) {
    const int il = kq * 16 + j;
    float acc = 0.f;
#pragma unroll
    for (int r = 0; r < 16; ++r) acc += wAs[il][r] * wbo[r];
    res[j] = f2bf(wv[j] + acc * 0.0625f);
  }
  s16x8 lo, hi;
#pragma unroll
  for (int j = 0; j < 8; ++j) {
    lo[j] = (short)res[j];
    hi[j] = (short)res[j + 8];
  }
  unsigned short* dst = Wt + (size_t)t * TILE_SH + kq * 2048 + col_local * 16;
  *(s16x8*)&dst[0] = lo;
  *(s16x8*)&dst[8] = hi;
}

// ---------------------------------------------------------------------------
// Kernel 3: 128x128 GEMM, BK=64, 4 waves (2x2), 32x32x16 MFMA, 2x2 frags/wave.
// Simple 2-phase double-buffer (compiler-scheduled), 64 KB LDS -> 2 blocks/CU.
// ---------------------------------------------------------------------------
__global__ __launch_bounds__(256) void gemm32_kernel(
    const unsigned short* __restrict__ At, const unsigned short* __restrict__ Wt,
    const float* __restrict__ bias, float* __restrict__ C) {
  __shared__ __align__(16) unsigned short As[2][TILE_SH];
  __shared__ __align__(16) unsigned short Bs[2][TILE_SH];

  const int orig = blockIdx.x;
  const int bid = (orig & 7) * 512 + (orig >> 3);  // XCD swizzle, 4096%8==0
  const int mt = bid >> 3;                         // 0..511
  const int nt = bid & 7;                          // 0..7
  const int batch = mt >> 5;                       // 32 m-tiles per batch
  const unsigned short* Abase = At + (size_t)mt * 16 * TILE_SH;
  const unsigned short* Bbase = Wt + ((size_t)batch * 8 + nt) * 16 * TILE_SH;

  const int tid = threadIdx.x;
  const int lane = tid & 63;
  const int wid = tid >> 6;
  const int wr = wid >> 1;   // 0..1
  const int wc = wid & 1;    // 0..1
  const int l31 = lane & 31;
  const int hi5 = lane >> 5;

  f32x16 acc[2][2] = {};

  // Per-wave staging: calls wid*4 .. wid*4+3 for both A and B.
#define STAGE(BUF, KT)                                                         \
  {                                                                            \
    const unsigned short* as_ = Abase + (size_t)(KT)*TILE_SH;                  \
    const unsigned short* bs_ = Bbase + (size_t)(KT)*TILE_SH;                  \
    _Pragma("unroll") for (int c_ = 0; c_ < 4; ++c_) {                         \
      const int call_ = wid * 4 + c_;                                          \
      GLDS(as_ + call_ * 512 + lane * 8, &As[BUF][call_ * 512]);               \
      GLDS(bs_ + call_ * 512 + lane * 8, &Bs[BUF][call_ * 512]);               \
    }                                                                          \
  }

  STAGE(0, 0);
  __syncthreads();

#pragma unroll 1
  for (int kt = 0; kt < 16; ++kt) {
    const int buf = kt & 1;
    if (kt < 15) STAGE(buf ^ 1, kt + 1);
    s16x8 a[2][4], bfr[2][4];
#pragma unroll
    for (int mf = 0; mf < 2; ++mf)
#pragma unroll
      for (int k4 = 0; k4 < 4; ++k4)
        a[mf][k4] = *(const s16x8*)&As[buf][k4 * 2048 +
                                           (wr * 64 + mf * 32 + l31) * 16 +
                                           hi5 * 8];
#pragma unroll
    for (int nf = 0; nf < 2; ++nf)
#pragma unroll
      for (int k4 = 0; k4 < 4; ++k4)
        bfr[nf][k4] = *(const s16x8*)&Bs[buf][k4 * 2048 +
                                              (wc * 64 + nf * 32 + l31) * 16 +
                                              hi5 * 8];
#pragma unroll
    for (int k4 = 0; k4 < 4; ++k4)
#pragma unroll
      for (int mf = 0; mf < 2; ++mf)
#pragma unroll
        for (int nf = 0; nf < 2; ++nf)
          acc[mf][nf] = __builtin_amdgcn_mfma_f32_32x32x16_bf16(
              a[mf][k4], bfr[nf][k4], acc[mf][nf], 0, 0, 0);
    __syncthreads();
  }

  // Epilogue: C layout col=lane&31, row=(reg&3)+8*(reg>>2)+4*(lane>>5).
  const int m0 = mt * 128, n0 = nt * 128;
#pragma unroll
  for (int nf = 0; nf < 2; ++nf) {
    const int col = n0 + wc * 64 + nf * 32 + l31;
    const float bv = bias[col];
#pragma unroll
    for (int mf = 0; mf < 2; ++mf) {
      const int rbase = m0 + wr * 64 + mf * 32 + hi5 * 4;
#pragma unroll
      for (int r = 0; r < 16; ++r) {
        const int row = rbase + (r & 3) + 8 * (r >> 2);
        C[(size_t)row * ND + col] = acc[mf][nf][r] + bv;
      }
    }
  }
}

// ---------------------------------------------------------------------------
extern "C" void kernel_launch(void* const* d_in, const int* in_sizes, int n_in,
                              void* d_out, int out_size, void* d_ws,
                              size_t ws_size, hipStream_t stream) {
  const float* input = (const float*)d_in[0];
  const float* skill_logits = (const float*)d_in[1];
  const float* weight = (const float*)d_in[2];
  const float* bias = (const float*)d_in[3];
  const float* Askills = (const float*)d_in[4];
  const float* Bskills = (const float*)d_in[5];
  const int* task_ids = (const int*)d_in[6];

  float* wA = (float*)d_ws;                                   // 1 MB
  float* wB = wA + 16 * 16384;                                // 1 MB
  unsigned short* Wt = (unsigned short*)(wB + 16 * 16384);    // 32 MB
  unsigned short* At = Wt + 16ull * 1024 * 1024;              // 128 MB

  route_wab_kernel<<<32, 256, 0, stream>>>(skill_logits, task_ids, Askills,
                                           Bskills, wA, wB);
  aconv_kernel<<<16384, 256, 0, stream>>>(input, At);
  weff_kernel<<<4096, 256, 0, stream>>>(weight, wA, wB, Wt);
  gemm32_kernel<<<4096, 256, 0, stream>>>(At, Wt, bias, (float*)d_out);
}

// Round 8
// 330.956 us; speedup vs baseline: 1.1600x; 1.1513x over previous
//
#include <hip/hip_runtime.h>
#include <hip/hip_bf16.h>
#include <math.h>

#define N_SKILLS 16

typedef __attribute__((ext_vector_type(8))) short s16x8;
typedef __attribute__((ext_vector_type(4))) float f32x4;

__device__ __forceinline__ unsigned short f2bf(float f) {
  unsigned int u = __float_as_uint(f);
  u += 0x7fffu + ((u >> 16) & 1u);
  return (unsigned short)(u >> 16);
}

#define GLDS(gsrc, ldst)                                                       \
  __builtin_amdgcn_global_load_lds(                                            \
      (const __attribute__((address_space(1))) unsigned int*)(gsrc),           \
      (__attribute__((address_space(3))) unsigned int*)(ldst), 16, 0, 0)

// ---------------------------------------------------------------------------
// Tile image layout (128 rows/cols x 64 k bf16 = 8192 shorts):
//   offset(row, klocal) = ((klocal>>3)*128 + row)*8 + (klocal&7)
// MFMA frag (16x16x32) read: lane(l15,kq), kk: 16B at ((kk*4+kq)*128+row)*8.
// ---------------------------------------------------------------------------

// route: grid 64 = b*4 + quarter. wA f32 [b][k*16+r]; wAt bf16 tile images
// [b][kt][((k&63)>>3)*16+r][k&7]; wBt bf16 [b][col*16+r] scaled by 1/16.
__global__ __launch_bounds__(256) void route_kernel(
    const float* __restrict__ skill_logits, const int* __restrict__ task_ids,
    const float* __restrict__ Askills, const float* __restrict__ Bskills,
    float* __restrict__ wA, unsigned short* __restrict__ wAt,
    unsigned short* __restrict__ wBt) {
  __shared__ float l[N_SKILLS];
  const int b = blockIdx.x >> 2, q = blockIdx.x & 3;
  const int tid = threadIdx.x;
  if (tid == 0) {
    int t = task_ids[b];
    float tmp[N_SKILLS];
    float s = 0.f;
    for (int k = 0; k < N_SKILLS; ++k) {
      float v = 1.f / (1.f + expf(-skill_logits[t * N_SKILLS + k]));
      tmp[k] = v;
      s += v;
    }
    float inv = 1.f / (s + 1e-12f);
    for (int k = 0; k < N_SKILLS; ++k) l[k] = tmp[k] * inv;
  }
  __syncthreads();
  for (int j = q * 4096 + tid; j < (q + 1) * 4096; j += 256) {
    float a = 0.f;
#pragma unroll
    for (int s = 0; s < 16; ++s) a += l[s] * Askills[s * 16384 + j];
    wA[b * 16384 + j] = a;
    const int k = j >> 4, r = j & 15;
    wAt[(b * 16 + (k >> 6)) * 1024 + (((k & 63) >> 3) * 16 + r) * 8 + (k & 7)] =
        f2bf(a);
    float v = 0.f;
#pragma unroll
    for (int s = 0; s < 16; ++s) v += l[s] * Bskills[s * 16384 + j];
    const int rr = j >> 10, col = j & 1023;
    wBt[b * 16384 + col * 16 + rr] = f2bf(v * 0.0625f);
  }
}

// aconv: input fp32 -> At bf16 tile images. Block = 64-row half of (mt,kt).
__global__ __launch_bounds__(256) void aconv_kernel(
    const float* __restrict__ A, unsigned short* __restrict__ At) {
  const int bx = blockIdx.x;  // tk*2 + rh
  const int rh = bx & 1;
  const int tk = bx >> 1;  // mt*16 + kt
  const int mt = tk >> 4, kt = tk & 15;
  const int tid = threadIdx.x;
  const int rowl = tid >> 2, kquad = tid & 3;
  const int rloc = rh * 64 + rowl;
  const float* src = A + (size_t)(mt * 128 + rloc) * 1024 + kt * 64 + kquad * 16;
  f32x4 v0 = *(const f32x4*)(src);
  f32x4 v1 = *(const f32x4*)(src + 4);
  f32x4 v2 = *(const f32x4*)(src + 8);
  f32x4 v3 = *(const f32x4*)(src + 12);
  s16x8 lo, hi;
#pragma unroll
  for (int j = 0; j < 4; ++j) {
    lo[j] = (short)f2bf(v0[j]);
    lo[j + 4] = (short)f2bf(v1[j]);
    hi[j] = (short)f2bf(v2[j]);
    hi[j + 4] = (short)f2bf(v3[j]);
  }
  unsigned short* dst = At + (size_t)tk * 8192 + ((kquad * 2) * 128 + rloc) * 8;
  *(s16x8*)&dst[0] = lo;
  *(s16x8*)&dst[1024] = hi;  // chunk kquad*2+1
}

// wconv: shared W -> Wt tile images (8 nt x 16 kt tiles of 128col x 64k).
__global__ __launch_bounds__(256) void wconv_kernel(
    const float* __restrict__ W, unsigned short* __restrict__ Wt) {
  const int bx = blockIdx.x;  // t*2 + ch
  const int ch = bx & 1;
  const int t = bx >> 1;  // nt*16 + kt
  const int nt = t >> 4, kt = t & 15;
  const int tid = threadIdx.x;
  const int c64 = tid >> 2, kq4 = tid & 3;
  const int col = ch * 64 + c64;
  const float* src = W + (size_t)(nt * 128 + col) * 1024 + kt * 64 + kq4 * 16;
  f32x4 v0 = *(const f32x4*)(src);
  f32x4 v1 = *(const f32x4*)(src + 4);
  f32x4 v2 = *(const f32x4*)(src + 8);
  f32x4 v3 = *(const f32x4*)(src + 12);
  s16x8 lo, hi;
#pragma unroll
  for (int j = 0; j < 4; ++j) {
    lo[j] = (short)f2bf(v0[j]);
    lo[j + 4] = (short)f2bf(v1[j]);
    hi[j] = (short)f2bf(v2[j]);
    hi[j + 4] = (short)f2bf(v3[j]);
  }
  unsigned short* dst = Wt + (size_t)t * 8192 + ((kq4 * 2) * 128 + col) * 8;
  *(s16x8*)&dst[0] = lo;
  *(s16x8*)&dst[1024] = hi;
}

// lora1 = A_bf16 @ wA (65536x1024 @ 1024x16), MFMA, no LDS, no barriers.
// Block = one mt (128 rows), 4 waves of 32 rows. Output f32 [row*16 + r].
__global__ __launch_bounds__(256) void lora1_kernel(
    const unsigned short* __restrict__ At, const unsigned short* __restrict__ wAt,
    float* __restrict__ lora1) {
  const int mt = blockIdx.x;  // 0..511
  const int batch = mt >> 5;
  const int tid = threadIdx.x;
  const int lane = tid & 63, w = tid >> 6;
  const int l15 = lane & 15, kq = lane >> 4;
  f32x4 acc[2] = {};
  const unsigned short* Ab = At + (size_t)mt * 16 * 8192;
  const unsigned short* Wb = wAt + batch * 16 * 1024;
#pragma unroll 1
  for (int kt = 0; kt < 16; ++kt) {
    const unsigned short* at = Ab + kt * 8192;
    const unsigned short* wt = Wb + kt * 1024;
#pragma unroll
    for (int kk = 0; kk < 2; ++kk) {
      s16x8 bfrag = *(const s16x8*)&wt[((kk * 4 + kq) * 16 + l15) * 8];
#pragma unroll
      for (int mf = 0; mf < 2; ++mf) {
        s16x8 af = *(const s16x8*)&at[((kk * 4 + kq) * 128 + w * 32 + mf * 16 + l15) * 8];
        acc[mf] = __builtin_amdgcn_mfma_f32_16x16x32_bf16(af, bfrag, acc[mf], 0, 0, 0);
      }
    }
  }
#pragma unroll
  for (int mf = 0; mf < 2; ++mf) {
    const int row = mt * 128 + w * 32 + mf * 16 + kq * 4;
#pragma unroll
    for (int jj = 0; jj < 4; ++jj)
      lora1[(size_t)(row + jj) * 16 + l15] = acc[mf][jj];
  }
}

// ---------------------------------------------------------------------------
// GEMM: C = A@W^T + lora1@wBt + bias. 128x128 tile, BK=64, 4 waves (2Mx2N),
// wave = 64x64 (4x4 frags). B staged in LDS (32KB dbuf); A frags DIRECT
// global->VGPR (no LDS round-trip). Simple 2-phase, compiler-scheduled.
// ---------------------------------------------------------------------------
__global__ __launch_bounds__(256, 3) void gemm_kernel(
    const unsigned short* __restrict__ At, const unsigned short* __restrict__ Wt,
    const unsigned short* __restrict__ wBt, const float* __restrict__ lora1,
    const float* __restrict__ bias, float* __restrict__ C) {
  __shared__ __align__(16) unsigned short Bs[2][8192];

  const int orig = blockIdx.x;
  const int bid = (orig & 7) * 512 + (orig >> 3);  // XCD swizzle, 4096%8==0
  const int mt = bid >> 3;  // 0..511
  const int nt = bid & 7;   // 0..7
  const int batch = mt >> 5;
  const unsigned short* Ab = At + (size_t)mt * 16 * 8192;
  const unsigned short* Bb = Wt + (size_t)nt * 16 * 8192;

  const int tid = threadIdx.x, lane = tid & 63, wid = tid >> 6;
  const int wr = wid >> 1, wc = wid & 1;
  const int l15 = lane & 15, kq = lane >> 4;

  f32x4 acc[4][4] = {};

#define STAGE_B(BUF, KT)                                                       \
  {                                                                            \
    const unsigned short* s_ = Bb + (size_t)(KT)*8192;                         \
    _Pragma("unroll") for (int c_ = 0; c_ < 4; ++c_) {                         \
      const int call_ = wid * 4 + c_;                                          \
      GLDS(s_ + call_ * 512 + lane * 8, &Bs[BUF][call_ * 512]);                \
    }                                                                          \
  }

  STAGE_B(0, 0);
  __syncthreads();

#pragma unroll 1
  for (int kt = 0; kt < 16; ++kt) {
    const int buf = kt & 1;
    if (kt < 15) STAGE_B(buf ^ 1, kt + 1);
    const unsigned short* at = Ab + (size_t)kt * 8192;
    s16x8 areg[2][4];
#pragma unroll
    for (int kk = 0; kk < 2; ++kk)
#pragma unroll
      for (int mf = 0; mf < 4; ++mf)
        areg[kk][mf] = *(const s16x8*)&at[((kk * 4 + kq) * 128 + wr * 64 + mf * 16 + l15) * 8];
#pragma unroll
    for (int kk = 0; kk < 2; ++kk) {
      s16x8 bfr[4];
#pragma unroll
      for (int nf = 0; nf < 4; ++nf)
        bfr[nf] = *(const s16x8*)&Bs[buf][((kk * 4 + kq) * 128 + wc * 64 + nf * 16 + l15) * 8];
#pragma unroll
      for (int mf = 0; mf < 4; ++mf)
#pragma unroll
        for (int nf = 0; nf < 4; ++nf)
          acc[mf][nf] = __builtin_amdgcn_mfma_f32_16x16x32_bf16(
              areg[kk][mf], bfr[nf], acc[mf][nf], 0, 0, 0);
    }
    __syncthreads();
  }

  const int m0 = mt * 128, n0 = nt * 128;

  // LoRA epilogue: acc += bf16(lora1) @ wBt  (K=32, rows 16..31 zero-padded).
  {
    s16x8 lafrag[4], wbfrag[4];
#pragma unroll
    for (int mf = 0; mf < 4; ++mf) {
      s16x8 v = {0, 0, 0, 0, 0, 0, 0, 0};
      if (kq < 2) {
        const float* lp = lora1 + (size_t)(m0 + wr * 64 + mf * 16 + l15) * 16 + kq * 8;
        f32x4 x0 = *(const f32x4*)lp;
        f32x4 x1 = *(const f32x4*)(lp + 4);
#pragma unroll
        for (int j = 0; j < 4; ++j) {
          v[j] = (short)f2bf(x0[j]);
          v[j + 4] = (short)f2bf(x1[j]);
        }
      }
      lafrag[mf] = v;
    }
#pragma unroll
    for (int nf = 0; nf < 4; ++nf) {
      s16x8 v = {0, 0, 0, 0, 0, 0, 0, 0};
      if (kq < 2)
        v = *(const s16x8*)&wBt[(size_t)batch * 16384 +
                                (n0 + wc * 64 + nf * 16 + l15) * 16 + kq * 8];
      wbfrag[nf] = v;
    }
#pragma unroll
    for (int mf = 0; mf < 4; ++mf)
#pragma unroll
      for (int nf = 0; nf < 4; ++nf)
        acc[mf][nf] = __builtin_amdgcn_mfma_f32_16x16x32_bf16(
            lafrag[mf], wbfrag[nf], acc[mf][nf], 0, 0, 0);
  }

  // bias + store
#pragma unroll
  for (int nf = 0; nf < 4; ++nf) {
    const int col = n0 + wc * 64 + nf * 16 + l15;
    const float bv = bias[col];
#pragma unroll
    for (int mf = 0; mf < 4; ++mf) {
      const int row = m0 + wr * 64 + mf * 16 + kq * 4;
#pragma unroll
      for (int j = 0; j < 4; ++j)
        C[(size_t)(row + j) * 1024 + col] = acc[mf][nf][j] + bv;
    }
  }
}

// ---------------------------------------------------------------------------
extern "C" void kernel_launch(void* const* d_in, const int* in_sizes, int n_in,
                              void* d_out, int out_size, void* d_ws,
                              size_t ws_size, hipStream_t stream) {
  const float* input = (const float*)d_in[0];
  const float* skill_logits = (const float*)d_in[1];
  const float* weight = (const float*)d_in[2];
  const float* bias = (const float*)d_in[3];
  const float* Askills = (const float*)d_in[4];
  const float* Bskills = (const float*)d_in[5];
  const int* task_ids = (const int*)d_in[6];

  float* wA = (float*)d_ws;                                    // 1 MB
  float* lora1 = wA + 262144;                                  // 4 MB
  unsigned short* wAt = (unsigned short*)(lora1 + 1048576);    // 512 KB
  unsigned short* wBt = wAt + 262144;                          // 512 KB
  unsigned short* Wt = wBt + 262144;                           // 2 MB
  unsigned short* At = Wt + 1048576;                           // 128 MB

  route_kernel<<<64, 256, 0, stream>>>(skill_logits, task_ids, Askills,
                                       Bskills, wA, wAt, wBt);
  wconv_kernel<<<256, 256, 0, stream>>>(weight, Wt);
  aconv_kernel<<<16384, 256, 0, stream>>>(input, At);
  lora1_kernel<<<512, 256, 0, stream>>>(At, wAt, lora1);
  gemm_kernel<<<4096, 256, 0, stream>>>(At, Wt, wBt, lora1, bias,
                                        (float*)d_out);
}